// Round 1
// baseline (2197.193 us; speedup 1.0000x reference)
//
#include <hip/hip_runtime.h>
#include <math.h>

// GCN 3-layer forward, N=100000 nodes, E=3200000 edges, F=256 -> 8 -> 4 -> 16.
// Strategy: per layer, aggregate in the smaller of {in,out} dims (aggregation
// commutes with the dense transform). Self-loops folded analytically as
// dis[n]^2 * feat[n] in the per-node finish kernels.

#define N_NODES 100000
#define N_EDGES 3200000
#define BLK 256

__device__ __forceinline__ float eluf(float v) {
  return v > 0.0f ? v : expm1f(v);
}

// Detect whether edge_index arrived as int64 (odd u32 words of first 64 all 0)
__global__ void detect_kernel(const unsigned int* __restrict__ ei, int* __restrict__ flag) {
  if (blockIdx.x == 0 && threadIdx.x == 0) {
    int is64 = 1;
    for (int i = 0; i < 32; ++i)
      if (ei[2 * i + 1] != 0u) { is64 = 0; break; }
    *flag = is64;
  }
}

__global__ void decode_kernel(const void* __restrict__ raw, const int* __restrict__ flag,
                              int* __restrict__ src, int* __restrict__ dst) {
  const int is64 = *flag;
  int tid = blockIdx.x * blockDim.x + threadIdx.x;
  int stride = gridDim.x * blockDim.x;
  if (is64) {
    const long long* p = (const long long*)raw;
    for (int i = tid; i < N_EDGES; i += stride) {
      src[i] = (int)p[i];
      dst[i] = (int)p[N_EDGES + i];
    }
  } else {
    const int* p = (const int*)raw;
    for (int i = tid; i < N_EDGES; i += stride) {
      src[i] = p[i];
      dst[i] = p[N_EDGES + i];
    }
  }
}

__global__ void deg_kernel(const int* __restrict__ dst, const float* __restrict__ w,
                           float* __restrict__ deg) {
  int tid = blockIdx.x * blockDim.x + threadIdx.x;
  int stride = gridDim.x * blockDim.x;
  for (int e = tid; e < N_EDGES; e += stride) {
    unsigned d = (unsigned)dst[e];
    if (d < (unsigned)N_NODES) atomicAdd(&deg[d], w[e]);
  }
}

__global__ void dis_kernel(float* __restrict__ degdis) {
  int n = blockIdx.x * blockDim.x + threadIdx.x;
  if (n < N_NODES) degdis[n] = rsqrtf(degdis[n] + 1.0f);  // +1 = self-loop weight
}

__global__ void norm_kernel(const int* __restrict__ src, const int* __restrict__ dst,
                            const float* __restrict__ w, const float* __restrict__ dis,
                            float* __restrict__ nrm) {
  int tid = blockIdx.x * blockDim.x + threadIdx.x;
  int stride = gridDim.x * blockDim.x;
  for (int e = tid; e < N_EDGES; e += stride) {
    unsigned s = (unsigned)src[e], d = (unsigned)dst[e];
    float ns = (s < (unsigned)N_NODES) ? dis[s] : 0.0f;
    float nd = (d < (unsigned)N_NODES) ? dis[d] : 0.0f;
    nrm[e] = ns * w[e] * nd;
  }
}

// x[N,256] @ W1[256,8] -> m1[N,8]; one wave per node row (64 lanes x float4).
__global__ __launch_bounds__(BLK) void transform1_kernel(const float* __restrict__ x,
                                                         const float* __restrict__ W1,
                                                         float* __restrict__ m1) {
  const int lane = threadIdx.x & 63;
  const int gwave = blockIdx.x * (BLK / 64) + (threadIdx.x >> 6);
  const int nwaves = gridDim.x * (BLK / 64);
  float wreg[4][8];
#pragma unroll
  for (int i = 0; i < 4; ++i)
#pragma unroll
    for (int j = 0; j < 8; ++j)
      wreg[i][j] = W1[(lane * 4 + i) * 8 + j];
  for (int n = gwave; n < N_NODES; n += nwaves) {
    float4 xv = *(const float4*)(x + (size_t)n * 256 + lane * 4);
    float acc[8];
#pragma unroll
    for (int j = 0; j < 8; ++j)
      acc[j] = xv.x * wreg[0][j] + xv.y * wreg[1][j] + xv.z * wreg[2][j] + xv.w * wreg[3][j];
#pragma unroll
    for (int off = 32; off > 0; off >>= 1)
#pragma unroll
      for (int j = 0; j < 8; ++j)
        acc[j] += __shfl_down(acc[j], off);
    if (lane == 0) {
      float4* o = (float4*)(m1 + (size_t)n * 8);
      o[0] = make_float4(acc[0], acc[1], acc[2], acc[3]);
      o[1] = make_float4(acc[4], acc[5], acc[6], acc[7]);
    }
  }
}

// Scatter-aggregate: out[dst] += norm[e] * feat[src], FEAT floats per node.
template <int FEAT>
__global__ void agg_kernel(const int* __restrict__ src, const int* __restrict__ dst,
                           const float* __restrict__ nrm, const float* __restrict__ feat,
                           float* __restrict__ out) {
  constexpr int P = FEAT / 4;  // float4 parts per edge
  const long long total = (long long)N_EDGES * P;
  long long tid = (long long)blockIdx.x * blockDim.x + threadIdx.x;
  long long stride = (long long)gridDim.x * blockDim.x;
  for (long long t = tid; t < total; t += stride) {
    int e = (int)(t / P);
    int p = (int)(t % P);
    unsigned s = (unsigned)src[e], d = (unsigned)dst[e];
    if (s >= (unsigned)N_NODES || d >= (unsigned)N_NODES) continue;
    float nr = nrm[e];
    float4 v = *(const float4*)(feat + (size_t)s * FEAT + p * 4);
    float* o = out + (size_t)d * FEAT + p * 4;
    atomicAdd(o + 0, nr * v.x);
    atomicAdd(o + 1, nr * v.y);
    atomicAdd(o + 2, nr * v.z);
    atomicAdd(o + 3, nr * v.w);
  }
}

// h1e = elu(h1 + dis^2*m1 + b1); m2 = h1e @ W2[8,4]
__global__ void finish1_kernel(const float* __restrict__ h1, const float* __restrict__ m1,
                               const float* __restrict__ dis, const float* __restrict__ b1,
                               const float* __restrict__ W2, float* __restrict__ m2) {
  int n = blockIdx.x * blockDim.x + threadIdx.x;
  if (n >= N_NODES) return;
  float di = dis[n];
  float self = di * di;
  float4 a0 = *(const float4*)(h1 + (size_t)n * 8);
  float4 a1 = *(const float4*)(h1 + (size_t)n * 8 + 4);
  float4 b0 = *(const float4*)(m1 + (size_t)n * 8);
  float4 b1v = *(const float4*)(m1 + (size_t)n * 8 + 4);
  float h[8];
  h[0] = eluf(a0.x + self * b0.x + b1[0]);
  h[1] = eluf(a0.y + self * b0.y + b1[1]);
  h[2] = eluf(a0.z + self * b0.z + b1[2]);
  h[3] = eluf(a0.w + self * b0.w + b1[3]);
  h[4] = eluf(a1.x + self * b1v.x + b1[4]);
  h[5] = eluf(a1.y + self * b1v.y + b1[5]);
  h[6] = eluf(a1.z + self * b1v.z + b1[6]);
  h[7] = eluf(a1.w + self * b1v.w + b1[7]);
  float o0 = 0.f, o1 = 0.f, o2 = 0.f, o3 = 0.f;
#pragma unroll
  for (int i = 0; i < 8; ++i) {
    float hi = h[i];
    o0 += hi * W2[i * 4 + 0];
    o1 += hi * W2[i * 4 + 1];
    o2 += hi * W2[i * 4 + 2];
    o3 += hi * W2[i * 4 + 3];
  }
  *(float4*)(m2 + (size_t)n * 4) = make_float4(o0, o1, o2, o3);
}

// h2e = elu(g2 + dis^2*m2 + b2)
__global__ void finish2_kernel(const float* __restrict__ g2, const float* __restrict__ m2,
                               const float* __restrict__ dis, const float* __restrict__ b2,
                               float* __restrict__ h2e) {
  int n = blockIdx.x * blockDim.x + threadIdx.x;
  if (n >= N_NODES) return;
  float di = dis[n];
  float self = di * di;
  float4 g = *(const float4*)(g2 + (size_t)n * 4);
  float4 m = *(const float4*)(m2 + (size_t)n * 4);
  float4 r;
  r.x = eluf(g.x + self * m.x + b2[0]);
  r.y = eluf(g.y + self * m.y + b2[1]);
  r.z = eluf(g.z + self * m.z + b2[2]);
  r.w = eluf(g.w + self * m.w + b2[3]);
  *(float4*)(h2e + (size_t)n * 4) = r;
}

// out = (g3 + dis^2*h2e) @ W3[4,16] + b3
__global__ void finish3_kernel(const float* __restrict__ g3, const float* __restrict__ h2e,
                               const float* __restrict__ dis, const float* __restrict__ b3,
                               const float* __restrict__ W3, float* __restrict__ out) {
  int n = blockIdx.x * blockDim.x + threadIdx.x;
  if (n >= N_NODES) return;
  float di = dis[n];
  float self = di * di;
  float4 a = *(const float4*)(g3 + (size_t)n * 4);
  float4 h = *(const float4*)(h2e + (size_t)n * 4);
  float g0 = a.x + self * h.x;
  float g1 = a.y + self * h.y;
  float g2v = a.z + self * h.z;
  float g3v = a.w + self * h.w;
  float o[16];
#pragma unroll
  for (int c = 0; c < 16; ++c)
    o[c] = b3[c] + g0 * W3[c] + g1 * W3[16 + c] + g2v * W3[32 + c] + g3v * W3[48 + c];
  float4* op = (float4*)(out + (size_t)n * 16);
  op[0] = make_float4(o[0], o[1], o[2], o[3]);
  op[1] = make_float4(o[4], o[5], o[6], o[7]);
  op[2] = make_float4(o[8], o[9], o[10], o[11]);
  op[3] = make_float4(o[12], o[13], o[14], o[15]);
}

extern "C" void kernel_launch(void* const* d_in, const int* in_sizes, int n_in,
                              void* d_out, int out_size, void* d_ws, size_t ws_size,
                              hipStream_t stream) {
  const float* x = (const float*)d_in[0];
  const void* ei = d_in[1];
  const float* w = (const float*)d_in[2];
  const float* W1 = (const float*)d_in[3];
  const float* b1 = (const float*)d_in[4];
  const float* W2 = (const float*)d_in[5];
  const float* b2 = (const float*)d_in[6];
  const float* W3 = (const float*)d_in[7];
  const float* b3 = (const float*)d_in[8];
  float* out = (float*)d_out;
  float* ws = (float*)d_ws;

  const size_t N = N_NODES, E = N_EDGES;
  // ws layout (4-byte words):
  float* dis = ws;                 // [N]   deg then dis (in place)
  float* h1 = ws + N;              // [8N]  layer-1 edge aggregate (atomic)
  float* g2 = ws + 9 * N;          // [4N]  layer-2 edge aggregate (atomic)
  float* g3 = ws + 13 * N;         // [4N]  layer-3 edge aggregate (atomic)
  float* nrm = ws + 17 * N;        // [E]
  float* m1 = ws + 17 * N + E;     // [8N]
  float* m2 = ws + 25 * N + E;     // [4N]
  float* h2e = ws + 29 * N + E;    // [4N]
  int* srcA = (int*)(ws + 33 * N + E);      // [E]
  int* dstA = (int*)(ws + 33 * N + 2 * E);  // [E]
  int* flag = (int*)(ws + 33 * N + 3 * E);  // [1]
  // total = 33N + 3E + 1 words ~= 51.6 MB

  // zero the atomic accumulators (dis, h1, g2, g3 are contiguous)
  hipMemsetAsync(d_ws, 0, 17 * N * sizeof(float), stream);

  detect_kernel<<<1, 64, 0, stream>>>((const unsigned int*)ei, flag);
  decode_kernel<<<2048, BLK, 0, stream>>>(ei, flag, srcA, dstA);
  deg_kernel<<<2048, BLK, 0, stream>>>(dstA, w, dis);
  dis_kernel<<<(N_NODES + BLK - 1) / BLK, BLK, 0, stream>>>(dis);
  norm_kernel<<<2048, BLK, 0, stream>>>(srcA, dstA, w, dis, nrm);
  transform1_kernel<<<4096, BLK, 0, stream>>>(x, W1, m1);
  agg_kernel<8><<<4096, BLK, 0, stream>>>(srcA, dstA, nrm, m1, h1);
  finish1_kernel<<<(N_NODES + BLK - 1) / BLK, BLK, 0, stream>>>(h1, m1, dis, b1, W2, m2);
  agg_kernel<4><<<2048, BLK, 0, stream>>>(srcA, dstA, nrm, m2, g2);
  finish2_kernel<<<(N_NODES + BLK - 1) / BLK, BLK, 0, stream>>>(g2, m2, dis, b2, h2e);
  agg_kernel<4><<<2048, BLK, 0, stream>>>(srcA, dstA, nrm, h2e, g3);
  finish3_kernel<<<(N_NODES + BLK - 1) / BLK, BLK, 0, stream>>>(g3, h2e, dis, b3, W3, out);
}

// Round 2
// 517.784 us; speedup vs baseline: 4.2435x; 4.2435x over previous
//
#include <hip/hip_runtime.h>
#include <math.h>

// GCN 3-layer forward, N=100000, E=3200000, F=256 -> 8 -> 4 -> 16.
// Round 2: replace per-edge float scatter-atomics (51.2M, 1285 us) with a
// per-call counting sort into dst-CSR (6.4M int/u64 atomics), then each
// layer's aggregation is an atomic-free gather + fused per-node epilogue.

#define N_NODES 100000
#define N_EDGES 3200000
#define BLK 256
#define SCAN_ITEMS 1024
#define NB_SCAN ((N_NODES + SCAN_ITEMS - 1) / SCAN_ITEMS)  // 98

__device__ __forceinline__ float eluf(float v) { return v > 0.0f ? v : expm1f(v); }

__device__ __forceinline__ int ld_edge(const void* __restrict__ raw, int is64, long long idx) {
  return is64 ? (int)((const long long*)raw)[idx] : ((const int*)raw)[idx];
}

// Detect whether edge_index arrived as int64 (odd u32 words of first 64 all 0)
__global__ void detect_kernel(const unsigned int* __restrict__ ei, int* __restrict__ flag) {
  if (blockIdx.x == 0 && threadIdx.x == 0) {
    int is64 = 1;
    for (int i = 0; i < 32; ++i)
      if (ei[2 * i + 1] != 0u) { is64 = 0; break; }
    *flag = is64;
  }
}

// packed[d] += (1 << 40) | round(w * 2^24): count in high 24b, fixpoint wsum low 40b
__global__ void hist_kernel(const void* __restrict__ raw, const int* __restrict__ flag,
                            const float* __restrict__ w,
                            unsigned long long* __restrict__ packed) {
  const int is64 = *flag;
  int tid = blockIdx.x * blockDim.x + threadIdx.x;
  int stride = gridDim.x * blockDim.x;
  for (int e = tid; e < N_EDGES; e += stride) {
    int d = ld_edge(raw, is64, (long long)N_EDGES + e);
    if ((unsigned)d >= (unsigned)N_NODES) continue;
    unsigned long long inc =
        (1ull << 40) | (unsigned long long)(w[e] * 16777216.0f + 0.5f);
    atomicAdd(&packed[d], inc);
  }
}

// Per-block sums of counts (1024 items / block)
__global__ __launch_bounds__(BLK) void scan1_kernel(const unsigned long long* __restrict__ packed,
                                                    int* __restrict__ blockSums) {
  __shared__ int wsum[4];
  int b = blockIdx.x, t = threadIdx.x;
  int i0 = b * SCAN_ITEMS + t * 4;
  int s = 0;
#pragma unroll
  for (int k = 0; k < 4; ++k)
    if (i0 + k < N_NODES) s += (int)(packed[i0 + k] >> 40);
  int lane = t & 63, wid = t >> 6;
#pragma unroll
  for (int off = 32; off > 0; off >>= 1) s += __shfl_down(s, off);
  if (lane == 0) wsum[wid] = s;
  __syncthreads();
  if (t == 0) blockSums[b] = wsum[0] + wsum[1] + wsum[2] + wsum[3];
}

// Serial exclusive scan of NB_SCAN block sums (98 values)
__global__ void scan2_kernel(int* __restrict__ blockSums) {
  if (threadIdx.x == 0 && blockIdx.x == 0) {
    int run = 0;
    for (int b = 0; b < NB_SCAN; ++b) {
      int v = blockSums[b];
      blockSums[b] = run;
      run += v;
    }
  }
}

// Final: offs[n] (exclusive scan), cursor[n]=offs[n], dis[n]=rsqrt(wdeg+1)
__global__ __launch_bounds__(BLK) void scan3_kernel(const unsigned long long* __restrict__ packed,
                                                    const int* __restrict__ blockSums,
                                                    int* __restrict__ offs,
                                                    int* __restrict__ cursor,
                                                    float* __restrict__ dis) {
  __shared__ int wtot[4];
  int b = blockIdx.x, t = threadIdx.x;
  int i0 = b * SCAN_ITEMS + t * 4;
  int c[4];
  int tsum = 0;
#pragma unroll
  for (int k = 0; k < 4; ++k) {
    unsigned long long p = (i0 + k < N_NODES) ? packed[i0 + k] : 0ull;
    c[k] = (int)(p >> 40);
    tsum += c[k];
    if (i0 + k < N_NODES)
      dis[i0 + k] = rsqrtf((float)(p & 0xFFFFFFFFFFull) * 5.9604644775390625e-8f + 1.0f);
  }
  int lane = t & 63, wid = t >> 6;
  int sc = tsum;
#pragma unroll
  for (int off = 1; off < 64; off <<= 1) {
    int v = __shfl_up(sc, off);
    if (lane >= off) sc += v;
  }
  if (lane == 63) wtot[wid] = sc;
  __syncthreads();
  int woff = 0;
  for (int i = 0; i < wid; ++i) woff += wtot[i];
  int base = blockSums[b] + woff + (sc - tsum);
#pragma unroll
  for (int k = 0; k < 4; ++k) {
    if (i0 + k < N_NODES) {
      offs[i0 + k] = base;
      cursor[i0 + k] = base;
    }
    base += c[k];
  }
}

// Scatter edges into CSR order: recs[pos] = {src, norm}
__global__ void scatter_kernel(const void* __restrict__ raw, const int* __restrict__ flag,
                               const float* __restrict__ w, const float* __restrict__ dis,
                               int* __restrict__ cursor, int2* __restrict__ recs) {
  const int is64 = *flag;
  int tid = blockIdx.x * blockDim.x + threadIdx.x;
  int stride = gridDim.x * blockDim.x;
  for (int e = tid; e < N_EDGES; e += stride) {
    int s = ld_edge(raw, is64, e);
    int d = ld_edge(raw, is64, (long long)N_EDGES + e);
    if ((unsigned)s >= (unsigned)N_NODES || (unsigned)d >= (unsigned)N_NODES) continue;
    float nr = dis[s] * w[e] * dis[d];
    int pos = atomicAdd(&cursor[d], 1);
    recs[pos] = make_int2(s, __float_as_int(nr));
  }
}

// x[N,256] @ W1[256,8] -> m1[N,8]; one wave per node row (64 lanes x float4).
__global__ __launch_bounds__(BLK) void transform1_kernel(const float* __restrict__ x,
                                                         const float* __restrict__ W1,
                                                         float* __restrict__ m1) {
  const int lane = threadIdx.x & 63;
  const int gwave = blockIdx.x * (BLK / 64) + (threadIdx.x >> 6);
  const int nwaves = gridDim.x * (BLK / 64);
  float wreg[4][8];
#pragma unroll
  for (int i = 0; i < 4; ++i)
#pragma unroll
    for (int j = 0; j < 8; ++j)
      wreg[i][j] = W1[(lane * 4 + i) * 8 + j];
  for (int n = gwave; n < N_NODES; n += nwaves) {
    float4 xv = *(const float4*)(x + (size_t)n * 256 + lane * 4);
    float acc[8];
#pragma unroll
    for (int j = 0; j < 8; ++j)
      acc[j] = xv.x * wreg[0][j] + xv.y * wreg[1][j] + xv.z * wreg[2][j] + xv.w * wreg[3][j];
#pragma unroll
    for (int off = 32; off > 0; off >>= 1)
#pragma unroll
      for (int j = 0; j < 8; ++j)
        acc[j] += __shfl_down(acc[j], off);
    if (lane == 0) {
      float4* o = (float4*)(m1 + (size_t)n * 8);
      o[0] = make_float4(acc[0], acc[1], acc[2], acc[3]);
      o[1] = make_float4(acc[4], acc[5], acc[6], acc[7]);
    }
  }
}

// Layer 1 fused: aggregate m1 over CSR edges + self-loop + b1 -> ELU -> @W2 -> m2
__global__ __launch_bounds__(BLK) void layer1_kernel(const unsigned long long* __restrict__ packed,
                                                     const int* __restrict__ offs,
                                                     const int2* __restrict__ recs,
                                                     const float* __restrict__ m1,
                                                     const float* __restrict__ dis,
                                                     const float* __restrict__ b1,
                                                     const float* __restrict__ W2,
                                                     float* __restrict__ m2) {
  int n = blockIdx.x * blockDim.x + threadIdx.x;
  if (n >= N_NODES) return;
  int beg = offs[n];
  int cnt = (int)(packed[n] >> 40);
  float a[8] = {0, 0, 0, 0, 0, 0, 0, 0};
  for (int i = 0; i < cnt; ++i) {
    int2 r = recs[beg + i];
    float nr = __int_as_float(r.y);
    const float4* f = (const float4*)(m1 + (size_t)r.x * 8);
    float4 v0 = f[0], v1 = f[1];
    a[0] += nr * v0.x; a[1] += nr * v0.y; a[2] += nr * v0.z; a[3] += nr * v0.w;
    a[4] += nr * v1.x; a[5] += nr * v1.y; a[6] += nr * v1.z; a[7] += nr * v1.w;
  }
  float di = dis[n], self = di * di;
  const float4* mm = (const float4*)(m1 + (size_t)n * 8);
  float4 s0 = mm[0], s1 = mm[1];
  float h[8];
  h[0] = eluf(a[0] + self * s0.x + b1[0]);
  h[1] = eluf(a[1] + self * s0.y + b1[1]);
  h[2] = eluf(a[2] + self * s0.z + b1[2]);
  h[3] = eluf(a[3] + self * s0.w + b1[3]);
  h[4] = eluf(a[4] + self * s1.x + b1[4]);
  h[5] = eluf(a[5] + self * s1.y + b1[5]);
  h[6] = eluf(a[6] + self * s1.z + b1[6]);
  h[7] = eluf(a[7] + self * s1.w + b1[7]);
  float o0 = 0.f, o1 = 0.f, o2 = 0.f, o3 = 0.f;
#pragma unroll
  for (int i = 0; i < 8; ++i) {
    float hi = h[i];
    o0 += hi * W2[i * 4 + 0];
    o1 += hi * W2[i * 4 + 1];
    o2 += hi * W2[i * 4 + 2];
    o3 += hi * W2[i * 4 + 3];
  }
  *(float4*)(m2 + (size_t)n * 4) = make_float4(o0, o1, o2, o3);
}

// Layer 2 fused: aggregate m2 + self + b2 -> ELU -> h2e
__global__ __launch_bounds__(BLK) void layer2_kernel(const unsigned long long* __restrict__ packed,
                                                     const int* __restrict__ offs,
                                                     const int2* __restrict__ recs,
                                                     const float* __restrict__ m2,
                                                     const float* __restrict__ dis,
                                                     const float* __restrict__ b2,
                                                     float* __restrict__ h2e) {
  int n = blockIdx.x * blockDim.x + threadIdx.x;
  if (n >= N_NODES) return;
  int beg = offs[n];
  int cnt = (int)(packed[n] >> 40);
  float a0 = 0.f, a1 = 0.f, a2 = 0.f, a3 = 0.f;
  for (int i = 0; i < cnt; ++i) {
    int2 r = recs[beg + i];
    float nr = __int_as_float(r.y);
    float4 v = *(const float4*)(m2 + (size_t)r.x * 4);
    a0 += nr * v.x; a1 += nr * v.y; a2 += nr * v.z; a3 += nr * v.w;
  }
  float di = dis[n], self = di * di;
  float4 s = *(const float4*)(m2 + (size_t)n * 4);
  float4 r;
  r.x = eluf(a0 + self * s.x + b2[0]);
  r.y = eluf(a1 + self * s.y + b2[1]);
  r.z = eluf(a2 + self * s.z + b2[2]);
  r.w = eluf(a3 + self * s.w + b2[3]);
  *(float4*)(h2e + (size_t)n * 4) = r;
}

// Layer 3 fused: aggregate h2e + self -> @W3 + b3 -> out[N,16]
__global__ __launch_bounds__(BLK) void layer3_kernel(const unsigned long long* __restrict__ packed,
                                                     const int* __restrict__ offs,
                                                     const int2* __restrict__ recs,
                                                     const float* __restrict__ h2e,
                                                     const float* __restrict__ dis,
                                                     const float* __restrict__ b3,
                                                     const float* __restrict__ W3,
                                                     float* __restrict__ out) {
  int n = blockIdx.x * blockDim.x + threadIdx.x;
  if (n >= N_NODES) return;
  int beg = offs[n];
  int cnt = (int)(packed[n] >> 40);
  float a0 = 0.f, a1 = 0.f, a2 = 0.f, a3 = 0.f;
  for (int i = 0; i < cnt; ++i) {
    int2 r = recs[beg + i];
    float nr = __int_as_float(r.y);
    float4 v = *(const float4*)(h2e + (size_t)r.x * 4);
    a0 += nr * v.x; a1 += nr * v.y; a2 += nr * v.z; a3 += nr * v.w;
  }
  float di = dis[n], self = di * di;
  float4 s = *(const float4*)(h2e + (size_t)n * 4);
  float g0 = a0 + self * s.x;
  float g1 = a1 + self * s.y;
  float g2 = a2 + self * s.z;
  float g3 = a3 + self * s.w;
  float o[16];
#pragma unroll
  for (int c = 0; c < 16; ++c)
    o[c] = b3[c] + g0 * W3[c] + g1 * W3[16 + c] + g2 * W3[32 + c] + g3 * W3[48 + c];
  float4* op = (float4*)(out + (size_t)n * 16);
  op[0] = make_float4(o[0], o[1], o[2], o[3]);
  op[1] = make_float4(o[4], o[5], o[6], o[7]);
  op[2] = make_float4(o[8], o[9], o[10], o[11]);
  op[3] = make_float4(o[12], o[13], o[14], o[15]);
}

extern "C" void kernel_launch(void* const* d_in, const int* in_sizes, int n_in,
                              void* d_out, int out_size, void* d_ws, size_t ws_size,
                              hipStream_t stream) {
  const float* x = (const float*)d_in[0];
  const void* ei = d_in[1];
  const float* w = (const float*)d_in[2];
  const float* W1 = (const float*)d_in[3];
  const float* b1 = (const float*)d_in[4];
  const float* W2 = (const float*)d_in[5];
  const float* b2 = (const float*)d_in[6];
  const float* W3 = (const float*)d_in[7];
  const float* b3 = (const float*)d_in[8];
  float* out = (float*)d_out;
  float* ws = (float*)d_ws;

  // ws layout (4-byte words); d_ws is 8B-aligned, packed/recs offsets are even.
  unsigned long long* packed = (unsigned long long*)ws;   // [N] u64      (200000 w)
  int* offs = (int*)(ws + 200000);                        // [N]          (100000 w)
  int* cursor = (int*)(ws + 300000);                      // [N]
  float* dis = ws + 400000;                               // [N]
  int* blockSums = (int*)(ws + 500000);                   // [128]
  int* flag = (int*)(ws + 500100);                        // [1]
  float* m1 = ws + 500128;                                // [8N]
  float* m2 = ws + 1300128;                               // [4N]
  float* h2e = ws + 1700128;                              // [4N]
  int2* recs = (int2*)(ws + 2100128);                     // [E] int2 (6.4M w)
  // total = 8,500,128 words ~= 34 MB

  hipMemsetAsync(packed, 0, N_NODES * sizeof(unsigned long long), stream);
  detect_kernel<<<1, 64, 0, stream>>>((const unsigned int*)ei, flag);
  hist_kernel<<<2048, BLK, 0, stream>>>(ei, flag, w, packed);
  scan1_kernel<<<NB_SCAN, BLK, 0, stream>>>(packed, blockSums);
  scan2_kernel<<<1, 64, 0, stream>>>(blockSums);
  scan3_kernel<<<NB_SCAN, BLK, 0, stream>>>(packed, blockSums, offs, cursor, dis);
  scatter_kernel<<<2048, BLK, 0, stream>>>(ei, flag, w, dis, cursor, recs);
  transform1_kernel<<<4096, BLK, 0, stream>>>(x, W1, m1);
  const int NBN = (N_NODES + BLK - 1) / BLK;
  layer1_kernel<<<NBN, BLK, 0, stream>>>(packed, offs, recs, m1, dis, b1, W2, m2);
  layer2_kernel<<<NBN, BLK, 0, stream>>>(packed, offs, recs, m2, dis, b2, h2e);
  layer3_kernel<<<NBN, BLK, 0, stream>>>(packed, offs, recs, h2e, dis, b3, W3, out);
}

// Round 3
// 494.571 us; speedup vs baseline: 4.4426x; 1.0469x over previous
//
#include <hip/hip_runtime.h>
#include <math.h>

// GCN 3-layer forward, N=100000, E=3200000, F=256 -> 8 -> 4 -> 16.
// Round 3: bucket-grouped edge records (782 buckets x 128 nodes) built with a
// two-phase chunked binning (write-amp ~1), then degree + all three layer
// aggregations run per-bucket with LDS accumulators. No global atomics, no
// random fine-grained global writes.

#define N_NODES 100000
#define N_EDGES 3200000
#define BN 128                       // nodes per bucket
#define NBUK 782                     // ceil(N/BN)
#define NCHUNK 256
#define CHUNK_E (N_EDGES / NCHUNK)   // 12500

__device__ __forceinline__ float eluf(float v) { return v > 0.0f ? v : expm1f(v); }

__device__ __forceinline__ int ld_edge(const void* __restrict__ raw, int is64, long long idx) {
  return is64 ? (int)((const long long*)raw)[idx] : ((const int*)raw)[idx];
}

// Detect whether edge_index arrived as int64 (odd u32 words of first 64 all 0)
__global__ void detect_kernel(const unsigned int* __restrict__ ei, int* __restrict__ flag) {
  if (blockIdx.x == 0 && threadIdx.x == 0) {
    int is64 = 1;
    for (int i = 0; i < 32; ++i)
      if (ei[2 * i + 1] != 0u) { is64 = 0; break; }
    *flag = is64;
  }
}

// Phase A: per-(chunk,bucket) edge counts via LDS histogram.
__global__ __launch_bounds__(512) void count_kernel(const void* __restrict__ raw,
                                                    const int* __restrict__ flag,
                                                    int* __restrict__ cnt) {
  __shared__ int c[NBUK];
  const int tid = threadIdx.x;
  for (int i = tid; i < NBUK; i += 512) c[i] = 0;
  __syncthreads();
  const int is64 = *flag;
  const int c0 = blockIdx.x * CHUNK_E;
  for (int e = c0 + tid; e < c0 + CHUNK_E; e += 512) {
    int d = ld_edge(raw, is64, (long long)N_EDGES + e);
    if ((unsigned)d < (unsigned)N_NODES) atomicAdd(&c[d >> 7], 1);
  }
  __syncthreads();
  for (int i = tid; i < NBUK; i += 512) cnt[blockIdx.x * NBUK + i] = c[i];
}

// Column-scan the count matrix (exclusive per bucket over chunks), then block
// exclusive scan of bucket totals -> bucketBase[NBUK+1].
__global__ __launch_bounds__(1024) void scan_kernel(int* __restrict__ cnt,
                                                    int* __restrict__ bucketBase) {
  __shared__ int sdata[1024];
  const int b = threadIdx.x;
  int run = 0;
  if (b < NBUK) {
    for (int c = 0; c < NCHUNK; ++c) {
      int v = cnt[c * NBUK + b];
      cnt[c * NBUK + b] = run;
      run += v;
    }
  }
  int val = run;
  sdata[b] = val;
  __syncthreads();
  for (int off = 1; off < 1024; off <<= 1) {
    int v = (b >= off) ? sdata[b - off] : 0;
    __syncthreads();
    sdata[b] += v;
    __syncthreads();
  }
  if (b < NBUK) bucketBase[b] = sdata[b] - val;
  if (b == NBUK - 1) bucketBase[NBUK] = sdata[b];
}

// Phase C: place records {src:17b | local:7b<<17, w} into bucket-grouped order.
__global__ __launch_bounds__(512) void place_kernel(const void* __restrict__ raw,
                                                    const int* __restrict__ flag,
                                                    const float* __restrict__ w,
                                                    const int* __restrict__ cnt,
                                                    const int* __restrict__ bucketBase,
                                                    int2* __restrict__ recs) {
  __shared__ int cur[NBUK];
  const int tid = threadIdx.x;
  for (int i = tid; i < NBUK; i += 512)
    cur[i] = cnt[blockIdx.x * NBUK + i] + bucketBase[i];
  __syncthreads();
  const int is64 = *flag;
  const int c0 = blockIdx.x * CHUNK_E;
  for (int e = c0 + tid; e < c0 + CHUNK_E; e += 512) {
    int s = ld_edge(raw, is64, e);
    int d = ld_edge(raw, is64, (long long)N_EDGES + e);
    if ((unsigned)s >= (unsigned)N_NODES || (unsigned)d >= (unsigned)N_NODES) continue;
    float wv = w[e];
    int bkt = d >> 7, loc = d & 127;
    int pos = atomicAdd(&cur[bkt], 1);
    recs[pos] = make_int2(s | (loc << 17), __float_as_int(wv));
  }
}

// Weighted degree per bucket via LDS float adds -> dis = rsqrt(deg + 1).
__global__ __launch_bounds__(256) void deg_kernel(const int2* __restrict__ recs,
                                                  const int* __restrict__ bucketBase,
                                                  float* __restrict__ dis) {
  __shared__ float acc[BN];
  const int b = blockIdx.x, tid = threadIdx.x;
  if (tid < BN) acc[tid] = 0.0f;
  __syncthreads();
  const int beg = bucketBase[b], end = bucketBase[b + 1];
  for (int i = beg + tid; i < end; i += 256) {
    int2 r = recs[i];
    atomicAdd(&acc[(r.x >> 17) & 127], __int_as_float(r.y));
  }
  __syncthreads();
  int n = b * BN + tid;
  if (tid < BN && n < N_NODES) dis[n] = rsqrtf(acc[tid] + 1.0f);
}

// x[N,256] @ W1[256,8] -> m1[N,8]; one wave per node row (64 lanes x float4).
__global__ __launch_bounds__(256) void transform1_kernel(const float* __restrict__ x,
                                                         const float* __restrict__ W1,
                                                         float* __restrict__ m1) {
  const int lane = threadIdx.x & 63;
  const int gwave = blockIdx.x * 4 + (threadIdx.x >> 6);
  const int nwaves = gridDim.x * 4;
  float wreg[4][8];
#pragma unroll
  for (int i = 0; i < 4; ++i)
#pragma unroll
    for (int j = 0; j < 8; ++j)
      wreg[i][j] = W1[(lane * 4 + i) * 8 + j];
  for (int n = gwave; n < N_NODES; n += nwaves) {
    float4 xv = *(const float4*)(x + (size_t)n * 256 + lane * 4);
    float acc[8];
#pragma unroll
    for (int j = 0; j < 8; ++j)
      acc[j] = xv.x * wreg[0][j] + xv.y * wreg[1][j] + xv.z * wreg[2][j] + xv.w * wreg[3][j];
#pragma unroll
    for (int off = 32; off > 0; off >>= 1)
#pragma unroll
      for (int j = 0; j < 8; ++j)
        acc[j] += __shfl_down(acc[j], off);
    if (lane == 0) {
      float4* o = (float4*)(m1 + (size_t)n * 8);
      o[0] = make_float4(acc[0], acc[1], acc[2], acc[3]);
      o[1] = make_float4(acc[4], acc[5], acc[6], acc[7]);
    }
  }
}

// Layer 1: per-bucket LDS accumulate of m1 messages + fused epilogue -> m2.
__global__ __launch_bounds__(256) void layer1_kernel(const int2* __restrict__ recs,
                                                     const int* __restrict__ bucketBase,
                                                     const float* __restrict__ m1,
                                                     const float* __restrict__ dis,
                                                     const float* __restrict__ b1,
                                                     const float* __restrict__ W2,
                                                     float* __restrict__ m2) {
  __shared__ float acc[BN][8];
  __shared__ float disL[BN];
  const int b = blockIdx.x, tid = threadIdx.x;
  if (tid < BN) {
    int n = b * BN + tid;
    disL[tid] = (n < N_NODES) ? dis[n] : 0.0f;
  }
  for (int i = tid; i < BN * 8; i += 256) ((float*)acc)[i] = 0.0f;
  __syncthreads();
  const int beg = bucketBase[b], end = bucketBase[b + 1];
  for (int i = beg + tid; i < end; i += 256) {
    int2 r = recs[i];
    int s = r.x & 0x1FFFF;
    int loc = (r.x >> 17) & 127;
    float nr = dis[s] * __int_as_float(r.y) * disL[loc];
    const float4* f = (const float4*)(m1 + (size_t)s * 8);
    float4 v0 = f[0], v1 = f[1];
    atomicAdd(&acc[loc][0], nr * v0.x);
    atomicAdd(&acc[loc][1], nr * v0.y);
    atomicAdd(&acc[loc][2], nr * v0.z);
    atomicAdd(&acc[loc][3], nr * v0.w);
    atomicAdd(&acc[loc][4], nr * v1.x);
    atomicAdd(&acc[loc][5], nr * v1.y);
    atomicAdd(&acc[loc][6], nr * v1.z);
    atomicAdd(&acc[loc][7], nr * v1.w);
  }
  __syncthreads();
  int n = b * BN + tid;
  if (tid < BN && n < N_NODES) {
    float di = disL[tid], self = di * di;
    const float4* mm = (const float4*)(m1 + (size_t)n * 8);
    float4 s0 = mm[0], s1 = mm[1];
    float h[8];
    h[0] = eluf(acc[tid][0] + self * s0.x + b1[0]);
    h[1] = eluf(acc[tid][1] + self * s0.y + b1[1]);
    h[2] = eluf(acc[tid][2] + self * s0.z + b1[2]);
    h[3] = eluf(acc[tid][3] + self * s0.w + b1[3]);
    h[4] = eluf(acc[tid][4] + self * s1.x + b1[4]);
    h[5] = eluf(acc[tid][5] + self * s1.y + b1[5]);
    h[6] = eluf(acc[tid][6] + self * s1.z + b1[6]);
    h[7] = eluf(acc[tid][7] + self * s1.w + b1[7]);
    float o0 = 0.f, o1 = 0.f, o2 = 0.f, o3 = 0.f;
#pragma unroll
    for (int i = 0; i < 8; ++i) {
      float hi = h[i];
      o0 += hi * W2[i * 4 + 0];
      o1 += hi * W2[i * 4 + 1];
      o2 += hi * W2[i * 4 + 2];
      o3 += hi * W2[i * 4 + 3];
    }
    *(float4*)(m2 + (size_t)n * 4) = make_float4(o0, o1, o2, o3);
  }
}

// Layer 2: per-bucket LDS accumulate of m2 + ELU epilogue -> h2e.
__global__ __launch_bounds__(256) void layer2_kernel(const int2* __restrict__ recs,
                                                     const int* __restrict__ bucketBase,
                                                     const float* __restrict__ m2,
                                                     const float* __restrict__ dis,
                                                     const float* __restrict__ b2,
                                                     float* __restrict__ h2e) {
  __shared__ float acc[BN][4];
  __shared__ float disL[BN];
  const int b = blockIdx.x, tid = threadIdx.x;
  if (tid < BN) {
    int n = b * BN + tid;
    disL[tid] = (n < N_NODES) ? dis[n] : 0.0f;
  }
  for (int i = tid; i < BN * 4; i += 256) ((float*)acc)[i] = 0.0f;
  __syncthreads();
  const int beg = bucketBase[b], end = bucketBase[b + 1];
  for (int i = beg + tid; i < end; i += 256) {
    int2 r = recs[i];
    int s = r.x & 0x1FFFF;
    int loc = (r.x >> 17) & 127;
    float nr = dis[s] * __int_as_float(r.y) * disL[loc];
    float4 v = *(const float4*)(m2 + (size_t)s * 4);
    atomicAdd(&acc[loc][0], nr * v.x);
    atomicAdd(&acc[loc][1], nr * v.y);
    atomicAdd(&acc[loc][2], nr * v.z);
    atomicAdd(&acc[loc][3], nr * v.w);
  }
  __syncthreads();
  int n = b * BN + tid;
  if (tid < BN && n < N_NODES) {
    float di = disL[tid], self = di * di;
    float4 s = *(const float4*)(m2 + (size_t)n * 4);
    float4 r;
    r.x = eluf(acc[tid][0] + self * s.x + b2[0]);
    r.y = eluf(acc[tid][1] + self * s.y + b2[1]);
    r.z = eluf(acc[tid][2] + self * s.z + b2[2]);
    r.w = eluf(acc[tid][3] + self * s.w + b2[3]);
    *(float4*)(h2e + (size_t)n * 4) = r;
  }
}

// Layer 3: per-bucket LDS accumulate of h2e + @W3 + b3 -> out[N,16].
__global__ __launch_bounds__(256) void layer3_kernel(const int2* __restrict__ recs,
                                                     const int* __restrict__ bucketBase,
                                                     const float* __restrict__ h2e,
                                                     const float* __restrict__ dis,
                                                     const float* __restrict__ b3,
                                                     const float* __restrict__ W3,
                                                     float* __restrict__ out) {
  __shared__ float acc[BN][4];
  __shared__ float disL[BN];
  const int b = blockIdx.x, tid = threadIdx.x;
  if (tid < BN) {
    int n = b * BN + tid;
    disL[tid] = (n < N_NODES) ? dis[n] : 0.0f;
  }
  for (int i = tid; i < BN * 4; i += 256) ((float*)acc)[i] = 0.0f;
  __syncthreads();
  const int beg = bucketBase[b], end = bucketBase[b + 1];
  for (int i = beg + tid; i < end; i += 256) {
    int2 r = recs[i];
    int s = r.x & 0x1FFFF;
    int loc = (r.x >> 17) & 127;
    float nr = dis[s] * __int_as_float(r.y) * disL[loc];
    float4 v = *(const float4*)(h2e + (size_t)s * 4);
    atomicAdd(&acc[loc][0], nr * v.x);
    atomicAdd(&acc[loc][1], nr * v.y);
    atomicAdd(&acc[loc][2], nr * v.z);
    atomicAdd(&acc[loc][3], nr * v.w);
  }
  __syncthreads();
  int n = b * BN + tid;
  if (tid < BN && n < N_NODES) {
    float di = disL[tid], self = di * di;
    float4 s = *(const float4*)(h2e + (size_t)n * 4);
    float g0 = acc[tid][0] + self * s.x;
    float g1 = acc[tid][1] + self * s.y;
    float g2 = acc[tid][2] + self * s.z;
    float g3 = acc[tid][3] + self * s.w;
    float o[16];
#pragma unroll
    for (int c = 0; c < 16; ++c)
      o[c] = b3[c] + g0 * W3[c] + g1 * W3[16 + c] + g2 * W3[32 + c] + g3 * W3[48 + c];
    float4* op = (float4*)(out + (size_t)n * 16);
    op[0] = make_float4(o[0], o[1], o[2], o[3]);
    op[1] = make_float4(o[4], o[5], o[6], o[7]);
    op[2] = make_float4(o[8], o[9], o[10], o[11]);
    op[3] = make_float4(o[12], o[13], o[14], o[15]);
  }
}

extern "C" void kernel_launch(void* const* d_in, const int* in_sizes, int n_in,
                              void* d_out, int out_size, void* d_ws, size_t ws_size,
                              hipStream_t stream) {
  const float* x = (const float*)d_in[0];
  const void* ei = d_in[1];
  const float* w = (const float*)d_in[2];
  const float* W1 = (const float*)d_in[3];
  const float* b1 = (const float*)d_in[4];
  const float* W2 = (const float*)d_in[5];
  const float* b2 = (const float*)d_in[6];
  const float* W3 = (const float*)d_in[7];
  const float* b3 = (const float*)d_in[8];
  float* out = (float*)d_out;
  float* ws = (float*)d_ws;

  // ws layout (4-byte words); recs first (8B-aligned at 0).
  int2* recs = (int2*)ws;                         // [E] int2     (6,400,000 w)
  float* m1 = ws + 6400000;                       // [8N]         (800,000 w)
  float* m2 = ws + 7200000;                       // [4N]         (400,000 w)
  float* h2e = ws + 7600000;                      // [4N]         (400,000 w)
  int* cnt = (int*)(ws + 8000000);                // [NCHUNK*NBUK] (200,192 w)
  int* bucketBase = (int*)(ws + 8200192);         // [NBUK+1]     (783 w)
  float* dis = ws + 8201000;                      // [N]          (100,000 w)
  int* flag = (int*)(ws + 8301000);               // [1]
  // total ~= 8,301,001 words ~= 33.2 MB

  detect_kernel<<<1, 64, 0, stream>>>((const unsigned int*)ei, flag);
  count_kernel<<<NCHUNK, 512, 0, stream>>>(ei, flag, cnt);
  scan_kernel<<<1, 1024, 0, stream>>>(cnt, bucketBase);
  place_kernel<<<NCHUNK, 512, 0, stream>>>(ei, flag, w, cnt, bucketBase, recs);
  deg_kernel<<<NBUK, 256, 0, stream>>>(recs, bucketBase, dis);
  transform1_kernel<<<4096, 256, 0, stream>>>(x, W1, m1);
  layer1_kernel<<<NBUK, 256, 0, stream>>>(recs, bucketBase, m1, dis, b1, W2, m2);
  layer2_kernel<<<NBUK, 256, 0, stream>>>(recs, bucketBase, m2, dis, b2, h2e);
  layer3_kernel<<<NBUK, 256, 0, stream>>>(recs, bucketBase, h2e, dis, b3, W3, out);
}

// Round 4
// 485.097 us; speedup vs baseline: 4.5294x; 1.0195x over previous
//
#include <hip/hip_runtime.h>
#include <math.h>

// GCN 3-layer forward, N=100000, E=3200000, F=256 -> 8 -> 4 -> 16.
// Round 4: BN=64 buckets (1563 blocks, ~6/CU occupancy), SoA LDS accumulators
// acc[j][loc] (bank = loc%32, ~2-way conflicts instead of 16-way), and
// dis-prescaled features (m1s = dis*m1) so layer kernels never gather dis[s].

#define N_NODES 100000
#define N_EDGES 3200000
#define BN 64                        // nodes per bucket
#define NBUK 1563                    // ceil(N/BN)
#define NCHUNK 256
#define CHUNK_E (N_EDGES / NCHUNK)   // 12500

__device__ __forceinline__ float eluf(float v) { return v > 0.0f ? v : expm1f(v); }

__device__ __forceinline__ int ld_edge(const void* __restrict__ raw, int is64, long long idx) {
  return is64 ? (int)((const long long*)raw)[idx] : ((const int*)raw)[idx];
}

// Detect whether edge_index arrived as int64 (odd u32 words of first 64 all 0)
__global__ void detect_kernel(const unsigned int* __restrict__ ei, int* __restrict__ flag) {
  if (blockIdx.x == 0 && threadIdx.x == 0) {
    int is64 = 1;
    for (int i = 0; i < 32; ++i)
      if (ei[2 * i + 1] != 0u) { is64 = 0; break; }
    *flag = is64;
  }
}

// Phase A: per-(chunk,bucket) edge counts via LDS histogram.
__global__ __launch_bounds__(512) void count_kernel(const void* __restrict__ raw,
                                                    const int* __restrict__ flag,
                                                    int* __restrict__ cnt) {
  __shared__ int c[NBUK];
  const int tid = threadIdx.x;
  for (int i = tid; i < NBUK; i += 512) c[i] = 0;
  __syncthreads();
  const int is64 = *flag;
  const int c0 = blockIdx.x * CHUNK_E;
  for (int e = c0 + tid; e < c0 + CHUNK_E; e += 512) {
    int d = ld_edge(raw, is64, (long long)N_EDGES + e);
    if ((unsigned)d < (unsigned)N_NODES) atomicAdd(&c[d >> 6], 1);
  }
  __syncthreads();
  for (int i = tid; i < NBUK; i += 512) cnt[blockIdx.x * NBUK + i] = c[i];
}

// Column-scan cnt (exclusive per bucket over chunks) + exclusive scan of
// bucket totals -> bucketBase[NBUK+1]. One block, 1024 threads, 2 buckets/thread.
__global__ __launch_bounds__(1024) void scan_kernel(int* __restrict__ cnt,
                                                    int* __restrict__ bucketBase) {
  __shared__ int sdata[1024];
  __shared__ int sTA;
  const int t = threadIdx.x;
  // column scan: bucket t
  int T0 = 0;
  {
    int run = 0;
    for (int c = 0; c < NCHUNK; ++c) {
      int idx = c * NBUK + t;
      int v = cnt[idx];
      cnt[idx] = run;
      run += v;
    }
    T0 = run;
  }
  // column scan: bucket 1024+t (if any)
  const int b1 = 1024 + t;
  int T1 = 0;
  if (b1 < NBUK) {
    int run = 0;
    for (int c = 0; c < NCHUNK; ++c) {
      int idx = c * NBUK + b1;
      int v = cnt[idx];
      cnt[idx] = run;
      run += v;
    }
    T1 = run;
  }
  // block inclusive scan of T0
  sdata[t] = T0;
  __syncthreads();
  for (int off = 1; off < 1024; off <<= 1) {
    int v = (t >= off) ? sdata[t - off] : 0;
    __syncthreads();
    sdata[t] += v;
    __syncthreads();
  }
  int incl0 = sdata[t];
  if (t == 1023) sTA = sdata[1023];
  __syncthreads();
  const int TA = sTA;
  // block inclusive scan of T1
  sdata[t] = T1;
  __syncthreads();
  for (int off = 1; off < 1024; off <<= 1) {
    int v = (t >= off) ? sdata[t - off] : 0;
    __syncthreads();
    sdata[t] += v;
    __syncthreads();
  }
  int incl1 = sdata[t];
  bucketBase[t] = incl0 - T0;
  if (b1 < NBUK) bucketBase[b1] = TA + incl1 - T1;
  if (b1 == NBUK - 1) bucketBase[NBUK] = TA + incl1;
}

// Phase C: place records {src:17b | local:6b<<17, w} into bucket-grouped order.
__global__ __launch_bounds__(512) void place_kernel(const void* __restrict__ raw,
                                                    const int* __restrict__ flag,
                                                    const float* __restrict__ w,
                                                    const int* __restrict__ cnt,
                                                    const int* __restrict__ bucketBase,
                                                    int2* __restrict__ recs) {
  __shared__ int cur[NBUK];
  const int tid = threadIdx.x;
  for (int i = tid; i < NBUK; i += 512)
    cur[i] = cnt[blockIdx.x * NBUK + i] + bucketBase[i];
  __syncthreads();
  const int is64 = *flag;
  const int c0 = blockIdx.x * CHUNK_E;
  for (int e = c0 + tid; e < c0 + CHUNK_E; e += 512) {
    int s = ld_edge(raw, is64, e);
    int d = ld_edge(raw, is64, (long long)N_EDGES + e);
    if ((unsigned)s >= (unsigned)N_NODES || (unsigned)d >= (unsigned)N_NODES) continue;
    float wv = w[e];
    int bkt = d >> 6, loc = d & 63;
    int pos = atomicAdd(&cur[bkt], 1);
    recs[pos] = make_int2(s | (loc << 17), __float_as_int(wv));
  }
}

// Weighted degree per bucket via LDS float adds -> dis = rsqrt(deg + 1).
__global__ __launch_bounds__(256) void deg_kernel(const int2* __restrict__ recs,
                                                  const int* __restrict__ bucketBase,
                                                  float* __restrict__ dis) {
  __shared__ float acc[BN];
  const int b = blockIdx.x, tid = threadIdx.x;
  if (tid < BN) acc[tid] = 0.0f;
  __syncthreads();
  const int beg = bucketBase[b], end = bucketBase[b + 1];
  for (int i = beg + tid; i < end; i += 256) {
    int2 r = recs[i];
    atomicAdd(&acc[(r.x >> 17) & 63], __int_as_float(r.y));
  }
  __syncthreads();
  int n = b * BN + tid;
  if (tid < BN && n < N_NODES) dis[n] = rsqrtf(acc[tid] + 1.0f);
}

// m1s[n] = dis[n] * (x[n] @ W1); one wave per node row (64 lanes x float4).
__global__ __launch_bounds__(256) void transform1_kernel(const float* __restrict__ x,
                                                         const float* __restrict__ W1,
                                                         const float* __restrict__ dis,
                                                         float* __restrict__ m1s) {
  const int lane = threadIdx.x & 63;
  const int gwave = blockIdx.x * 4 + (threadIdx.x >> 6);
  const int nwaves = gridDim.x * 4;
  float wreg[4][8];
#pragma unroll
  for (int i = 0; i < 4; ++i)
#pragma unroll
    for (int j = 0; j < 8; ++j)
      wreg[i][j] = W1[(lane * 4 + i) * 8 + j];
  for (int n = gwave; n < N_NODES; n += nwaves) {
    float4 xv = *(const float4*)(x + (size_t)n * 256 + lane * 4);
    float acc[8];
#pragma unroll
    for (int j = 0; j < 8; ++j)
      acc[j] = xv.x * wreg[0][j] + xv.y * wreg[1][j] + xv.z * wreg[2][j] + xv.w * wreg[3][j];
#pragma unroll
    for (int off = 32; off > 0; off >>= 1)
#pragma unroll
      for (int j = 0; j < 8; ++j)
        acc[j] += __shfl_down(acc[j], off);
    if (lane == 0) {
      float di = dis[n];
      float4* o = (float4*)(m1s + (size_t)n * 8);
      o[0] = make_float4(di * acc[0], di * acc[1], di * acc[2], di * acc[3]);
      o[1] = make_float4(di * acc[4], di * acc[5], di * acc[6], di * acc[7]);
    }
  }
}

// Layer 1: agg = sum w*disL[loc]*m1s[s] + dis[n]*m1s[n]; h=elu(agg+b1);
// m2s[n] = dis[n] * (h @ W2).
__global__ __launch_bounds__(256) void layer1_kernel(const int2* __restrict__ recs,
                                                     const int* __restrict__ bucketBase,
                                                     const float* __restrict__ m1s,
                                                     const float* __restrict__ dis,
                                                     const float* __restrict__ b1,
                                                     const float* __restrict__ W2,
                                                     float* __restrict__ m2s) {
  __shared__ float acc[8][BN];
  __shared__ float disL[BN];
  const int b = blockIdx.x, tid = threadIdx.x;
  if (tid < BN) {
    int n = b * BN + tid;
    disL[tid] = (n < N_NODES) ? dis[n] : 0.0f;
  }
  for (int i = tid; i < 8 * BN; i += 256) ((float*)acc)[i] = 0.0f;
  __syncthreads();
  const int beg = bucketBase[b], end = bucketBase[b + 1];
  for (int i = beg + tid; i < end; i += 256) {
    int2 r = recs[i];
    int s = r.x & 0x1FFFF;
    int loc = (r.x >> 17) & 63;
    float nw = __int_as_float(r.y) * disL[loc];
    const float4* f = (const float4*)(m1s + (size_t)s * 8);
    float4 v0 = f[0], v1 = f[1];
    atomicAdd(&acc[0][loc], nw * v0.x);
    atomicAdd(&acc[1][loc], nw * v0.y);
    atomicAdd(&acc[2][loc], nw * v0.z);
    atomicAdd(&acc[3][loc], nw * v0.w);
    atomicAdd(&acc[4][loc], nw * v1.x);
    atomicAdd(&acc[5][loc], nw * v1.y);
    atomicAdd(&acc[6][loc], nw * v1.z);
    atomicAdd(&acc[7][loc], nw * v1.w);
  }
  __syncthreads();
  int n = b * BN + tid;
  if (tid < BN && n < N_NODES) {
    float di = disL[tid];
    const float4* mm = (const float4*)(m1s + (size_t)n * 8);
    float4 s0 = mm[0], s1 = mm[1];
    float h[8];
    h[0] = eluf(acc[0][tid] + di * s0.x + b1[0]);
    h[1] = eluf(acc[1][tid] + di * s0.y + b1[1]);
    h[2] = eluf(acc[2][tid] + di * s0.z + b1[2]);
    h[3] = eluf(acc[3][tid] + di * s0.w + b1[3]);
    h[4] = eluf(acc[4][tid] + di * s1.x + b1[4]);
    h[5] = eluf(acc[5][tid] + di * s1.y + b1[5]);
    h[6] = eluf(acc[6][tid] + di * s1.z + b1[6]);
    h[7] = eluf(acc[7][tid] + di * s1.w + b1[7]);
    float o0 = 0.f, o1 = 0.f, o2 = 0.f, o3 = 0.f;
#pragma unroll
    for (int i = 0; i < 8; ++i) {
      float hi = h[i];
      o0 += hi * W2[i * 4 + 0];
      o1 += hi * W2[i * 4 + 1];
      o2 += hi * W2[i * 4 + 2];
      o3 += hi * W2[i * 4 + 3];
    }
    *(float4*)(m2s + (size_t)n * 4) = make_float4(di * o0, di * o1, di * o2, di * o3);
  }
}

// Layer 2: agg = sum w*disL*m2s[s] + dis[n]*m2s[n]; h2s[n] = dis[n]*elu(agg+b2).
__global__ __launch_bounds__(256) void layer2_kernel(const int2* __restrict__ recs,
                                                     const int* __restrict__ bucketBase,
                                                     const float* __restrict__ m2s,
                                                     const float* __restrict__ dis,
                                                     const float* __restrict__ b2,
                                                     float* __restrict__ h2s) {
  __shared__ float acc[4][BN];
  __shared__ float disL[BN];
  const int b = blockIdx.x, tid = threadIdx.x;
  if (tid < BN) {
    int n = b * BN + tid;
    disL[tid] = (n < N_NODES) ? dis[n] : 0.0f;
  }
  for (int i = tid; i < 4 * BN; i += 256) ((float*)acc)[i] = 0.0f;
  __syncthreads();
  const int beg = bucketBase[b], end = bucketBase[b + 1];
  for (int i = beg + tid; i < end; i += 256) {
    int2 r = recs[i];
    int s = r.x & 0x1FFFF;
    int loc = (r.x >> 17) & 63;
    float nw = __int_as_float(r.y) * disL[loc];
    float4 v = *(const float4*)(m2s + (size_t)s * 4);
    atomicAdd(&acc[0][loc], nw * v.x);
    atomicAdd(&acc[1][loc], nw * v.y);
    atomicAdd(&acc[2][loc], nw * v.z);
    atomicAdd(&acc[3][loc], nw * v.w);
  }
  __syncthreads();
  int n = b * BN + tid;
  if (tid < BN && n < N_NODES) {
    float di = disL[tid];
    float4 s = *(const float4*)(m2s + (size_t)n * 4);
    float4 r;
    r.x = di * eluf(acc[0][tid] + di * s.x + b2[0]);
    r.y = di * eluf(acc[1][tid] + di * s.y + b2[1]);
    r.z = di * eluf(acc[2][tid] + di * s.z + b2[2]);
    r.w = di * eluf(acc[3][tid] + di * s.w + b2[3]);
    *(float4*)(h2s + (size_t)n * 4) = r;
  }
}

// Layer 3: agg = sum w*disL*h2s[s] + dis[n]*h2s[n]; out = agg @ W3 + b3.
__global__ __launch_bounds__(256) void layer3_kernel(const int2* __restrict__ recs,
                                                     const int* __restrict__ bucketBase,
                                                     const float* __restrict__ h2s,
                                                     const float* __restrict__ dis,
                                                     const float* __restrict__ b3,
                                                     const float* __restrict__ W3,
                                                     float* __restrict__ out) {
  __shared__ float acc[4][BN];
  __shared__ float disL[BN];
  const int b = blockIdx.x, tid = threadIdx.x;
  if (tid < BN) {
    int n = b * BN + tid;
    disL[tid] = (n < N_NODES) ? dis[n] : 0.0f;
  }
  for (int i = tid; i < 4 * BN; i += 256) ((float*)acc)[i] = 0.0f;
  __syncthreads();
  const int beg = bucketBase[b], end = bucketBase[b + 1];
  for (int i = beg + tid; i < end; i += 256) {
    int2 r = recs[i];
    int s = r.x & 0x1FFFF;
    int loc = (r.x >> 17) & 63;
    float nw = __int_as_float(r.y) * disL[loc];
    float4 v = *(const float4*)(h2s + (size_t)s * 4);
    atomicAdd(&acc[0][loc], nw * v.x);
    atomicAdd(&acc[1][loc], nw * v.y);
    atomicAdd(&acc[2][loc], nw * v.z);
    atomicAdd(&acc[3][loc], nw * v.w);
  }
  __syncthreads();
  int n = b * BN + tid;
  if (tid < BN && n < N_NODES) {
    float di = disL[tid];
    float4 s = *(const float4*)(h2s + (size_t)n * 4);
    float g0 = acc[0][tid] + di * s.x;
    float g1 = acc[1][tid] + di * s.y;
    float g2 = acc[2][tid] + di * s.z;
    float g3 = acc[3][tid] + di * s.w;
    float o[16];
#pragma unroll
    for (int c = 0; c < 16; ++c)
      o[c] = b3[c] + g0 * W3[c] + g1 * W3[16 + c] + g2 * W3[32 + c] + g3 * W3[48 + c];
    float4* op = (float4*)(out + (size_t)n * 16);
    op[0] = make_float4(o[0], o[1], o[2], o[3]);
    op[1] = make_float4(o[4], o[5], o[6], o[7]);
    op[2] = make_float4(o[8], o[9], o[10], o[11]);
    op[3] = make_float4(o[12], o[13], o[14], o[15]);
  }
}

extern "C" void kernel_launch(void* const* d_in, const int* in_sizes, int n_in,
                              void* d_out, int out_size, void* d_ws, size_t ws_size,
                              hipStream_t stream) {
  const float* x = (const float*)d_in[0];
  const void* ei = d_in[1];
  const float* w = (const float*)d_in[2];
  const float* W1 = (const float*)d_in[3];
  const float* b1 = (const float*)d_in[4];
  const float* W2 = (const float*)d_in[5];
  const float* b2 = (const float*)d_in[6];
  const float* W3 = (const float*)d_in[7];
  const float* b3 = (const float*)d_in[8];
  float* out = (float*)d_out;
  float* ws = (float*)d_ws;

  // ws layout (4-byte words); recs first (8B-aligned at 0).
  int2* recs = (int2*)ws;                         // [E] int2      (6,400,000 w)
  float* m1s = ws + 6400000;                      // [8N]          (800,000 w)
  float* m2s = ws + 7200000;                      // [4N]          (400,000 w)
  float* h2s = ws + 7600000;                      // [4N]          (400,000 w)
  int* cnt = (int*)(ws + 8000000);                // [NCHUNK*NBUK] (400,128 w)
  int* bucketBase = (int*)(ws + 8400128);         // [NBUK+1]      (1,564 w)
  float* dis = ws + 8401692;                      // [N]           (100,000 w)
  int* flag = (int*)(ws + 8501692);               // [1]
  // total ~= 8,501,693 words ~= 34 MB

  detect_kernel<<<1, 64, 0, stream>>>((const unsigned int*)ei, flag);
  count_kernel<<<NCHUNK, 512, 0, stream>>>(ei, flag, cnt);
  scan_kernel<<<1, 1024, 0, stream>>>(cnt, bucketBase);
  place_kernel<<<NCHUNK, 512, 0, stream>>>(ei, flag, w, cnt, bucketBase, recs);
  deg_kernel<<<NBUK, 256, 0, stream>>>(recs, bucketBase, dis);
  transform1_kernel<<<4096, 256, 0, stream>>>(x, W1, dis, m1s);
  layer1_kernel<<<NBUK, 256, 0, stream>>>(recs, bucketBase, m1s, dis, b1, W2, m2s);
  layer2_kernel<<<NBUK, 256, 0, stream>>>(recs, bucketBase, m2s, dis, b2, h2s);
  layer3_kernel<<<NBUK, 256, 0, stream>>>(recs, bucketBase, h2s, dis, b3, W3, out);
}